// Round 5
// baseline (117.384 us; speedup 1.0000x reference)
//
#include <hip/hip_runtime.h>
#include <hip/hip_fp16.h>

#define W 256
#define NA 180
#define SPLIT 4
#define ROWBYTES 580          // 290 halfs = 145 words (odd word count -> conflict-free)
#define ROWS 259              // y' 0..258; data rows 1..256 (pixel y + 1)
// data cols 2..257 (pixel x + 2); guards: cols 0,1,258,259 and rows 0,257,258

__global__ __launch_bounds__(1024) void radon_kernel(
    const float* __restrict__ x, const int* __restrict__ index_p,
    float* __restrict__ out)
{
    __shared__ __half simg[ROWS * 290];   // 150,220 B

    const int a = blockIdx.x;        // angle 0..179
    const int n = blockIdx.y;        // batch
    const int tid = threadIdx.x;
    const int c = tid & (W - 1);     // column 0..255
    const int s = tid >> 8;          // r-chunk 0..3 (wave-uniform)

    const float* __restrict__ img = x + (size_t)n * W * W;

    // ---- guard zero-fill (disjoint from data cells -> one barrier total) ----
    {
        unsigned* wp = (unsigned*)simg;
        if (tid < 435) {                       // rows 0,257,258: 3 x 145 words
            const int rr = tid / 145;
            const int w = tid - rr * 145;
            const int row = (rr == 0) ? 0 : (256 + rr);   // 0,257,258
            wp[row * 145 + w] = 0u;
        } else if (tid < 947) {                // col guards, rows 1..256
            const int i = tid - 435;           // 0..511
            const int row = 1 + (i >> 1);
            const int w = (i & 1) ? 129 : 0;   // halfs {258,259} : {0,1}
            wp[row * 145 + w] = 0u;
        }
    }

    // ---- stage image -> LDS fp16 (no swizzle) ----
    {
        const float4* img4 = (const float4*)img;
        #pragma unroll
        for (int k = 0; k < 16; ++k) {
            const int g = k * 1024 + tid;      // float4 group
            const int row = (g >> 6) + 1;      // 1..256
            const int m = g & 63;
            const float4 v = img4[g];
            const __half2 h01 = __floats2half2_rn(v.x, v.y);
            const __half2 h23 = __floats2half2_rn(v.z, v.w);
            char* base = (char*)simg + row * ROWBYTES + 8 * m + 4;  // col 4m+2
            *(unsigned*)(base)     = *(const unsigned*)&h01;
            *(unsigned*)(base + 4) = *(const unsigned*)&h23;
        }
    }
    __syncthreads();

    const int index = *index_p;
    const int seg[6] = {1, 26, 51, 77, 102, 128};
    const int t0 = seg[4 - index];
    const int t1 = seg[4 - index + 1];

    float sa, ca;
    sincosf((float)a * 0.017453292519943295f, &sa, &ca);

    const float xc = ((2.0f * (float)c + 1.0f) * (1.0f / (float)W)) - 1.0f;
    // biased bases: +2 in x, +1 in y
    const float bx = fmaf(128.0f * ca, xc, 127.5f + 2.0f);
    const float by = fmaf(-128.0f * sa, xc, 127.5f + 1.0f);

    const int r1lo = 128 - t1;
    const int r0lo = 128 - t0, r0hi = 127 + t0;
    const int total = 2 * t1;
    const int chunk = (total + SPLIT - 1) / SPLIT;
    const int rs = r1lo + s * chunk;
    const int re = min(rs + chunk, r1lo + total);

    float sum0 = 0.0f, sum1 = 0.0f;
    const char* S = (const char*)simg;

#define TAP(SUM0, SUM1)                                                      \
    {                                                                        \
        float ix = fmaf(sa, rf, bx);                                         \
        float iy = fmaf(ca, rf, by);                                         \
        ix = fminf(fmaxf(ix, 1.0f), 258.0f);                                 \
        iy = fminf(fmaxf(iy, 0.0f), 257.0f);                                 \
        const float ix0f = floorf(ix);                                       \
        const float iy0f = floorf(iy);                                       \
        const float wx = ix - ix0f;                                          \
        const float wy = iy - iy0f;                                          \
        const int x0 = (int)ix0f;                                            \
        const int y0 = (int)iy0f;                                            \
        const __half* p = (const __half*)(S + y0 * ROWBYTES + x0 * 2);       \
        const float v00 = __half2float(p[0]);                                \
        const float v01 = __half2float(p[1]);                                \
        const float v10 = __half2float(p[290]);                              \
        const float v11 = __half2float(p[291]);                              \
        const float top = fmaf(wx, v01 - v00, v00);                          \
        const float bot = fmaf(wx, v11 - v10, v10);                          \
        const float val = fmaf(wy, bot - top, top);                          \
        SUM1;                                                                \
        SUM0;                                                                \
    }

    // segment A: [rs, min(re, r0lo))  -> sum1 only
    {
        const int e = min(re, r0lo);
        float rf = (float)rs - 127.5f;
        for (int r = rs; r < e; ++r, rf += 1.0f) TAP(, sum1 += val)
    }
    // segment B: [max(rs,r0lo), min(re, r0hi+1)) -> both
    {
        const int b = max(rs, r0lo);
        const int e = min(re, r0hi + 1);
        float rf = (float)b - 127.5f;
        for (int r = b; r < e; ++r, rf += 1.0f) TAP(sum0 += val, sum1 += val)
    }
    // segment C: [max(rs, r0hi+1), re) -> sum1 only
    {
        const int b = max(rs, r0hi + 1);
        float rf = (float)b - 127.5f;
        for (int r = b; r < re; ++r, rf += 1.0f) TAP(, sum1 += val)
    }
#undef TAP

    // ---- reduce partials; reuse simg as scratch ----
    __syncthreads();
    float* red = (float*)simg;                 // 8 KB of 150 KB
    red[(0 * SPLIT + s) * W + c] = sum0;
    red[(1 * SPLIT + s) * W + c] = sum1;
    __syncthreads();

    if (s == 0) {
        const float acc0 = red[0 * W + c] + red[1 * W + c] + red[2 * W + c] + red[3 * W + c];
        const float* r1p = red + SPLIT * W;
        const float acc1 = r1p[0 * W + c] + r1p[1 * W + c] + r1p[2 * W + c] + r1p[3 * W + c];
        out[(((size_t)n * 2 + 0) * W + c) * NA + a] = acc0 * (1.0f / (float)(2 * t0));
        out[(((size_t)n * 2 + 1) * W + c) * NA + a] = acc1 * (1.0f / (float)(2 * t1));
    }
}

extern "C" void kernel_launch(void* const* d_in, const int* in_sizes, int n_in,
                              void* d_out, int out_size, void* d_ws, size_t ws_size,
                              hipStream_t stream) {
    const float* x = (const float*)d_in[0];
    const int* index_p = (const int*)d_in[1];
    float* out = (float*)d_out;
    const int N = in_sizes[0] / (W * W); // 4
    dim3 grid(NA, N);
    radon_kernel<<<grid, 1024, 0, stream>>>(x, index_p, out);
}

// Round 6
// 117.033 us; speedup vs baseline: 1.0030x; 1.0030x over previous
//
#include <hip/hip_runtime.h>
#include <hip/hip_fp16.h>

#define W 256
#define NA 180
#define SPLIT 4
#define ROWBYTES 580          // 290 halfs = 145 words (odd word stride -> vertical walks hit all 32 banks)
#define ROWS 259              // y' 0..258; data rows 1..256 (pixel y + 1)
// data cols 2..257 (pixel x + 2); guards: cols 0,1,258,259 and rows 0,257,258

__global__ __launch_bounds__(1024) void radon_kernel(
    const float* __restrict__ x, const int* __restrict__ index_p,
    float* __restrict__ out)
{
    __shared__ __half simg[ROWS * 290];   // 150,220 B

    const int a = blockIdx.x;        // angle 0..179
    const int n = blockIdx.y;        // batch
    const int tid = threadIdx.x;
    const int c = tid & (W - 1);     // column 0..255
    const int s = tid >> 8;          // r-chunk 0..3 (wave-uniform)

    const float* __restrict__ img = x + (size_t)n * W * W;

    // ---- guard zero-fill (disjoint from data cells -> no barrier needed before staging) ----
    {
        unsigned* wp = (unsigned*)simg;
        if (tid < 435) {                       // rows 0,257,258: 3 x 145 words
            const int rr = tid / 145;
            const int w = tid - rr * 145;
            const int row = (rr == 0) ? 0 : (256 + rr);   // 0,257,258
            wp[row * 145 + w] = 0u;
        } else if (tid < 947) {                // col guards, rows 1..256
            const int i = tid - 435;           // 0..511
            const int row = 1 + (i >> 1);
            const int w = (i & 1) ? 129 : 0;   // halfs {258,259} : {0,1}
            wp[row * 145 + w] = 0u;
        }
    }

    // ---- stage image -> LDS fp16 (no swizzle) ----
    {
        const float4* img4 = (const float4*)img;
        #pragma unroll
        for (int k = 0; k < 16; ++k) {
            const int g = k * 1024 + tid;      // float4 group
            const int row = (g >> 6) + 1;      // 1..256
            const int m = g & 63;
            const float4 v = img4[g];
            const __half2 h01 = __floats2half2_rn(v.x, v.y);
            const __half2 h23 = __floats2half2_rn(v.z, v.w);
            char* base = (char*)simg + row * ROWBYTES + 8 * m + 4;  // col 4m+2
            *(unsigned*)(base)     = *(const unsigned*)&h01;
            *(unsigned*)(base + 4) = *(const unsigned*)&h23;
        }
    }
    __syncthreads();

    const int index = *index_p;
    const int seg[6] = {1, 26, 51, 77, 102, 128};
    const int t0 = seg[4 - index];
    const int t1 = seg[4 - index + 1];

    float sa, ca;
    sincosf((float)a * 0.017453292519943295f, &sa, &ca);

    const float xc = ((2.0f * (float)c + 1.0f) * (1.0f / (float)W)) - 1.0f;
    // biased bases: +2 in x, +1 in y (floor(v)+k == floor(v+k))
    const float bx = fmaf(128.0f * ca, xc, 127.5f + 2.0f);
    const float by = fmaf(-128.0f * sa, xc, 127.5f + 1.0f);

    const int r1lo = 128 - t1;
    const int r0lo = 128 - t0, r0hi = 127 + t0;
    const int total = 2 * t1;
    const int chunk = (total + SPLIT - 1) / SPLIT;
    const int rs = r1lo + s * chunk;
    const int re = min(rs + chunk, r1lo + total);

    float sum0 = 0.0f, sum1 = 0.0f;
    const char* S = (const char*)simg;

    float rf = (float)rs - 127.5f;
    #pragma unroll 4
    for (int r = rs; r < re; ++r, rf += 1.0f) {
        float ix = fmaf(sa, rf, bx);
        float iy = fmaf(ca, rf, by);
        ix = fminf(fmaxf(ix, 1.0f), 258.0f);   // clamp == per-tap zeroing via guard cells
        iy = fminf(fmaxf(iy, 0.0f), 257.0f);
        const float ix0f = floorf(ix);
        const float iy0f = floorf(iy);
        const float wx = ix - ix0f;
        const float wy = iy - iy0f;
        const int x0 = (int)ix0f;
        const int y0 = (int)iy0f;

        const __half* p = (const __half*)(S + y0 * ROWBYTES + x0 * 2);
        const float v00 = __half2float(p[0]);
        const float v01 = __half2float(p[1]);
        const float v10 = __half2float(p[290]);
        const float v11 = __half2float(p[291]);

        const float top = fmaf(wx, v01 - v00, v00);
        const float bot = fmaf(wx, v11 - v10, v10);
        const float val = fmaf(wy, bot - top, top);

        sum1 += val;
        sum0 += (r >= r0lo && r <= r0hi) ? val : 0.0f;
    }

    // ---- reduce partials; reuse simg as scratch ----
    __syncthreads();
    float* red = (float*)simg;                 // 8 KB of 150 KB
    red[(0 * SPLIT + s) * W + c] = sum0;
    red[(1 * SPLIT + s) * W + c] = sum1;
    __syncthreads();

    if (s == 0) {
        const float acc0 = red[0 * W + c] + red[1 * W + c] + red[2 * W + c] + red[3 * W + c];
        const float* r1p = red + SPLIT * W;
        const float acc1 = r1p[0 * W + c] + r1p[1 * W + c] + r1p[2 * W + c] + r1p[3 * W + c];
        out[(((size_t)n * 2 + 0) * W + c) * NA + a] = acc0 * (1.0f / (float)(2 * t0));
        out[(((size_t)n * 2 + 1) * W + c) * NA + a] = acc1 * (1.0f / (float)(2 * t1));
    }
}

extern "C" void kernel_launch(void* const* d_in, const int* in_sizes, int n_in,
                              void* d_out, int out_size, void* d_ws, size_t ws_size,
                              hipStream_t stream) {
    const float* x = (const float*)d_in[0];
    const int* index_p = (const int*)d_in[1];
    float* out = (float*)d_out;
    const int N = in_sizes[0] / (W * W); // 4
    dim3 grid(NA, N);
    radon_kernel<<<grid, 1024, 0, stream>>>(x, index_p, out);
}

// Round 7
// 49.213 us; speedup vs baseline: 2.3852x; 2.3781x over previous
//
#include <hip/hip_runtime.h>
#include <hip/hip_fp16.h>

#define W 256
#define NA 180
#define SPLIT 4
#define ROWBYTES 580          // 290 halfs = 145 words; odd word stride -> vertical walks hit all 32 banks
#define ROWS 259              // y' 0..258; data rows 1..256 (pixel y + 1)
// data cols 2..257 (pixel x + 2); guards: cols 0,1,258,259 and rows 0,257,258

__global__ __launch_bounds__(1024) void radon_kernel(
    const float* __restrict__ x, const int* __restrict__ index_p,
    float* __restrict__ out)
{
    __shared__ __half simg[ROWS * 290];   // 150,220 B

    const int a = blockIdx.x;        // angle 0..179
    const int n = blockIdx.y;        // batch
    const int tid = threadIdx.x;
    const int c = tid & (W - 1);     // column 0..255
    const int s = tid >> 8;          // r-chunk 0..3 (wave-uniform)

    const float* __restrict__ img = x + (size_t)n * W * W;

    // ---- guard zero-fill (disjoint words from staged data -> one barrier total) ----
    {
        unsigned* wp = (unsigned*)simg;
        if (tid < 435) {                       // rows 0,257,258: 3 x 145 words
            const int rr = tid / 145;
            const int w = tid - rr * 145;
            const int row = (rr == 0) ? 0 : (256 + rr);   // 0,257,258
            wp[row * 145 + w] = 0u;
        } else if (tid < 947) {                // col guards, rows 1..256
            const int i = tid - 435;           // 0..511
            const int row = 1 + (i >> 1);
            const int w = (i & 1) ? 129 : 0;   // halfs {258,259} : {0,1}
            wp[row * 145 + w] = 0u;
        }
    }

    // ---- stage image -> LDS fp16 ----
    {
        const float4* img4 = (const float4*)img;
        #pragma unroll
        for (int k = 0; k < 16; ++k) {
            const int g = k * 1024 + tid;      // float4 group
            const int row = (g >> 6) + 1;      // 1..256
            const int m = g & 63;
            const float4 v = img4[g];
            const __half2 h01 = __floats2half2_rn(v.x, v.y);
            const __half2 h23 = __floats2half2_rn(v.z, v.w);
            char* base = (char*)simg + row * ROWBYTES + 8 * m + 4;  // col 4m+2
            *(unsigned*)(base)     = *(const unsigned*)&h01;
            *(unsigned*)(base + 4) = *(const unsigned*)&h23;
        }
    }
    __syncthreads();

    const int index = *index_p;
    const int seg[6] = {1, 26, 51, 77, 102, 128};
    const int t0 = seg[4 - index];
    const int t1 = seg[4 - index + 1];

    float sa, ca;
    sincosf((float)a * 0.017453292519943295f, &sa, &ca);

    const float xc = ((2.0f * (float)c + 1.0f) * (1.0f / (float)W)) - 1.0f;
    // biased bases: +2 in x, +1 in y (floor(v)+k == floor(v+k))
    const float bx = fmaf(128.0f * ca, xc, 127.5f + 2.0f);
    const float by = fmaf(-128.0f * sa, xc, 127.5f + 1.0f);

    const int r1lo = 128 - t1;
    const int r0lo = 128 - t0, r0hi = 127 + t0;
    const int total = 2 * t1;
    const int chunk = (total + SPLIT - 1) / SPLIT;
    const int rs = r1lo + s * chunk;
    const int re = min(rs + chunk, r1lo + total);

    float sum0 = 0.0f, sum1 = 0.0f;
    const char* S = (const char*)simg;

    float rf = (float)rs - 127.5f;
    #pragma unroll 4
    for (int r = rs; r < re; ++r, rf += 1.0f) {
        float ix = fmaf(sa, rf, bx);
        float iy = fmaf(ca, rf, by);
        ix = fminf(fmaxf(ix, 1.0f), 258.0f);   // clamp == per-tap zeroing via guard cells
        iy = fminf(fmaxf(iy, 0.0f), 257.0f);
        const float ix0f = floorf(ix);
        const float iy0f = floorf(iy);
        const float wx = ix - ix0f;
        const float wy = iy - iy0f;
        const int x0 = (int)ix0f;
        const int y0 = (int)iy0f;

        // Four independent addresses, made mutually opaque so the compiler
        // CANNOT merge adjacent u16 pairs into (unaligned) b32 reads.
        const int base = y0 * ROWBYTES + x0 * 2;
        int a00 = base;
        int a01 = base + 2;
        int a10 = base + ROWBYTES;
        int a11 = base + ROWBYTES + 2;
        asm volatile("" : "+v"(a00), "+v"(a01), "+v"(a10), "+v"(a11));

        const float v00 = __half2float(*(const __half*)(S + a00));
        const float v01 = __half2float(*(const __half*)(S + a01));
        const float v10 = __half2float(*(const __half*)(S + a10));
        const float v11 = __half2float(*(const __half*)(S + a11));

        const float top = fmaf(wx, v01 - v00, v00);
        const float bot = fmaf(wx, v11 - v10, v10);
        const float val = fmaf(wy, bot - top, top);

        sum1 += val;
        if (r >= r0lo && r <= r0hi) sum0 += val;
    }

    // ---- reduce partials; reuse simg as scratch ----
    __syncthreads();
    float* red = (float*)simg;                 // 8 KB of 150 KB
    red[(0 * SPLIT + s) * W + c] = sum0;
    red[(1 * SPLIT + s) * W + c] = sum1;
    __syncthreads();

    if (s == 0) {
        const float acc0 = red[0 * W + c] + red[1 * W + c] + red[2 * W + c] + red[3 * W + c];
        const float* r1p = red + SPLIT * W;
        const float acc1 = r1p[0 * W + c] + r1p[1 * W + c] + r1p[2 * W + c] + r1p[3 * W + c];
        out[(((size_t)n * 2 + 0) * W + c) * NA + a] = acc0 * (1.0f / (float)(2 * t0));
        out[(((size_t)n * 2 + 1) * W + c) * NA + a] = acc1 * (1.0f / (float)(2 * t1));
    }
}

extern "C" void kernel_launch(void* const* d_in, const int* in_sizes, int n_in,
                              void* d_out, int out_size, void* d_ws, size_t ws_size,
                              hipStream_t stream) {
    const float* x = (const float*)d_in[0];
    const int* index_p = (const int*)d_in[1];
    float* out = (float*)d_out;
    const int N = in_sizes[0] / (W * W); // 4
    dim3 grid(NA, N);
    radon_kernel<<<grid, 1024, 0, stream>>>(x, index_p, out);
}